// Round 4
// baseline (54.337 us; speedup 1.0000x reference)
//
#include <hip/hip_runtime.h>

#define DISP_W 1.0f
#define MAT_W  0.1f
#define CD_W   0.5f

typedef _Float16 half8 __attribute__((ext_vector_type(8)));
typedef float f32x16 __attribute__((ext_vector_type(16)));

constexpr int BB = 4;           // batch
constexpr int NN = 8192;        // points per cloud
constexpr int THREADS = 256;    // 4 waves
constexpr int IB = 128;         // A-rows per block (4 waves x 32)
constexpr int JR = 512;         // B-cols per block
constexpr int NIB = NN / IB;    // 64
constexpr int NJB = NN / JR;    // 16
constexpr int NCHUNK = JR / 32; // 16
constexpr int GRID = 2 * BB * NIB * NJB;  // 8192

// One MFMA tile = 32x32 pairwise squared distances (verified layout, round 3):
//  A: [xh yh zh  xh yh zh  xl yl | zl cah cal 1 1 0 0 0]
//  B: [uxh uyh uzh uxl uyl uzl uxh uyh | uzh 1 1 cbh cbl 0 0 0]  (u = -2*B-point)
// Row-mins only (two directions handle p->t and t->p); partials written
// indexed (no atomics, no ws init needed).
__global__ __launch_bounds__(THREADS, 6)
void chamfer_mfma(const float* __restrict__ pred_disp,
                  const float* __restrict__ target_disp,
                  const float* __restrict__ tmpl,
                  float* __restrict__ rowpart)
{
    int bx = blockIdx.x;
    int jBlk = bx & (NJB - 1);
    int iBlk = (bx >> 4) & (NIB - 1);
    int b    = (bx >> 10) & (BB - 1);
    int dir  = bx >> 12;

    const float* aD = (dir ? target_disp : pred_disp) + (size_t)b * NN * 3;
    const float* bD = (dir ? pred_disp : target_disp) + (size_t)b * NN * 3;
    const float* tp = tmpl + (size_t)b * NN * 3;

    __shared__ half8 sBhi[JR];   // 8 KB
    __shared__ half8 sBlo[JR];   // 8 KB
    __shared__ float sRow[IB];   // 512 B

    const int tid  = threadIdx.x;
    const int lane = tid & 63;
    const int w    = tid >> 6;
    const int hi   = lane >> 5;
    const int li   = lane & 31;

    // ---- stage B fragments ----
    const int jBase = jBlk * JR;
    #pragma unroll
    for (int k = 0; k < JR / THREADS; ++k) {
        int j  = k * THREADS + tid;
        int j3 = (jBase + j) * 3;
        float x = tp[j3 + 0] + bD[j3 + 0];
        float y = tp[j3 + 1] + bD[j3 + 1];
        float z = tp[j3 + 2] + bD[j3 + 2];
        float cb = fmaf(x, x, fmaf(y, y, z * z));
        float ux = -2.0f * x, uy = -2.0f * y, uz = -2.0f * z;
        _Float16 uxh = (_Float16)ux; _Float16 uxl = (_Float16)(ux - (float)uxh);
        _Float16 uyh = (_Float16)uy; _Float16 uyl = (_Float16)(uy - (float)uyh);
        _Float16 uzh = (_Float16)uz; _Float16 uzl = (_Float16)(uz - (float)uzh);
        _Float16 cbh = (_Float16)cb; _Float16 cbl = (_Float16)(cb - (float)cbh);
        half8 vhi, vlo;
        vhi[0]=uxh; vhi[1]=uyh; vhi[2]=uzh; vhi[3]=uxl; vhi[4]=uyl; vhi[5]=uzl; vhi[6]=uxh; vhi[7]=uyh;
        vlo[0]=uzh; vlo[1]=(_Float16)1.0f; vlo[2]=(_Float16)1.0f; vlo[3]=cbh; vlo[4]=cbl;
        vlo[5]=(_Float16)0.0f; vlo[6]=(_Float16)0.0f; vlo[7]=(_Float16)0.0f;
        sBhi[j] = vhi;
        sBlo[j] = vlo;
    }

    // ---- A fragment (wave's 32 rows; lanes l and l+32 share a point) ----
    int i  = iBlk * IB + w * 32 + li;
    int i3 = i * 3;
    float ax = tp[i3 + 0] + aD[i3 + 0];
    float ay = tp[i3 + 1] + aD[i3 + 1];
    float az = tp[i3 + 2] + aD[i3 + 2];
    float ca = fmaf(ax, ax, fmaf(ay, ay, az * az));
    _Float16 xh = (_Float16)ax; _Float16 xl = (_Float16)(ax - (float)xh);
    _Float16 yh = (_Float16)ay; _Float16 yl = (_Float16)(ay - (float)yh);
    _Float16 zh = (_Float16)az; _Float16 zl = (_Float16)(az - (float)zh);
    _Float16 cah = (_Float16)ca; _Float16 cal = (_Float16)(ca - (float)cah);
    half8 aF;
    if (hi == 0) {
        aF[0]=xh; aF[1]=yh; aF[2]=zh; aF[3]=xh; aF[4]=yh; aF[5]=zh; aF[6]=xl; aF[7]=yl;
    } else {
        aF[0]=zl; aF[1]=cah; aF[2]=cal; aF[3]=(_Float16)1.0f; aF[4]=(_Float16)1.0f;
        aF[5]=(_Float16)0.0f; aF[6]=(_Float16)0.0f; aF[7]=(_Float16)0.0f;
    }

    __syncthreads();

    f32x16 kZero = {0.f,0.f,0.f,0.f, 0.f,0.f,0.f,0.f, 0.f,0.f,0.f,0.f, 0.f,0.f,0.f,0.f};
    const half8* baseB = hi ? sBlo : sBhi;
    float rm[16];
    #pragma unroll
    for (int r = 0; r < 16; ++r) rm[r] = 1.0e30f;

    #pragma unroll 4
    for (int c = 0; c < NCHUNK; ++c) {
        half8 bF = baseB[c * 32 + li];
        f32x16 acc = __builtin_amdgcn_mfma_f32_32x32x16_f16(aF, bF, kZero, 0, 0, 0);
        #pragma unroll
        for (int r = 0; r < 16; ++r) rm[r] = fminf(rm[r], acc[r]);
    }

    // ---- row mins: butterfly across the 32 col-lanes (hi halves independent) ----
    #pragma unroll
    for (int r = 0; r < 16; ++r) {
        float v = rm[r];
        v = fminf(v, __shfl_xor(v, 1, 64));
        v = fminf(v, __shfl_xor(v, 2, 64));
        v = fminf(v, __shfl_xor(v, 4, 64));
        v = fminf(v, __shfl_xor(v, 8, 64));
        v = fminf(v, __shfl_xor(v, 16, 64));
        rm[r] = v;
    }
    if (li == 0) {
        #pragma unroll
        for (int r = 0; r < 16; ++r)
            sRow[w * 32 + (r & 3) + 8 * (r >> 2) + 4 * hi] = rm[r];
    }
    __syncthreads();

    // coalesced partial write: rowpart[dir][b][jBlk][iBlk*IB + tid]
    if (tid < IB) {
        size_t base = ((size_t)(dir * BB + b) * NJB + jBlk) * NN + iBlk * IB;
        rowpart[base + tid] = sRow[tid];
    }
}

__global__ __launch_bounds__(256)
void final_reduce(const float* __restrict__ pred_disp,
                  const float* __restrict__ target_disp,
                  const float* __restrict__ pred_mat,
                  const float* __restrict__ target_mat,
                  const float* __restrict__ rowpart,
                  float* __restrict__ out)
{
    const int NDISP = BB * NN * 3;   // 98304
    const int NROWS = 2 * BB * NN;   // 65536

    int gtid = blockIdx.x * blockDim.x + threadIdx.x;
    int gstride = gridDim.x * blockDim.x;

    float dsum = 0.0f;
    for (int i = gtid; i < NDISP; i += gstride)
        dsum += fabsf(pred_disp[i] - target_disp[i]);

    float msum = 0.0f;
    for (int t = gtid; t < NROWS; t += gstride) {
        int db = t >> 13;            // dir*BB + b
        int i  = t & (NN - 1);
        const float* p = rowpart + (size_t)db * NJB * NN + i;
        float m = 1.0e30f;
        #pragma unroll
        for (int jb = 0; jb < NJB; ++jb)
            m = fminf(m, p[(size_t)jb * NN]);
        msum += fmaxf(m, 0.0f);      // clamp tiny negatives from dot-form
    }

    float acc = dsum * (DISP_W / (float)NDISP)
              + msum * (CD_W / (float)(BB * NN));

    if (gtid < 2 * BB) {
        float d = pred_mat[gtid] - target_mat[gtid];
        acc += d * d * (MAT_W / (float)(2 * BB));
    }

    for (int off = 32; off > 0; off >>= 1)
        acc += __shfl_down(acc, off, 64);

    __shared__ float wsum[4];
    if ((threadIdx.x & 63) == 0) wsum[threadIdx.x >> 6] = acc;
    __syncthreads();
    if (threadIdx.x == 0)
        atomicAdd(out, wsum[0] + wsum[1] + wsum[2] + wsum[3]);
}

extern "C" void kernel_launch(void* const* d_in, const int* in_sizes, int n_in,
                              void* d_out, int out_size, void* d_ws, size_t ws_size,
                              hipStream_t stream) {
    const float* pred_disp   = (const float*)d_in[0];
    const float* pred_mat    = (const float*)d_in[1];
    const float* target_disp = (const float*)d_in[2];
    const float* target_mat  = (const float*)d_in[3];
    const float* tmpl        = (const float*)d_in[4];

    float* rowpart = (float*)d_ws;        // 2*BB*NJB*NN floats = 4 MB, fully overwritten
    float* out = (float*)d_out;

    hipMemsetAsync(d_out, 0, sizeof(float), stream);

    chamfer_mfma<<<GRID, THREADS, 0, stream>>>(pred_disp, target_disp, tmpl, rowpart);
    final_reduce<<<256, 256, 0, stream>>>(pred_disp, target_disp, pred_mat, target_mat,
                                          rowpart, out);
}